// Round 3
// baseline (7833.444 us; speedup 1.0000x reference)
//
#include <hip/hip_runtime.h>
#include <stdint.h>
#include <stddef.h>

typedef __attribute__((ext_vector_type(8))) short bf16x8;
typedef __attribute__((ext_vector_type(4))) float f32x4;

#define NBLK 128
#define NTHR 512          // 8 waves: 2 waves/SIMD TLP, K split 8 ways
#define S_LEN 512
#define HD   1024
#define IDIM 512

#define MFMA16 __builtin_amdgcn_mfma_f32_16x16x32_bf16

__device__ __forceinline__ float bf2f(uint16_t u){
  union { uint32_t i; float f; } v; v.i = ((uint32_t)u) << 16; return v.f;
}
__device__ __forceinline__ uint16_t f2bf(float f){
  union { float f; uint32_t i; } v; v.f = f;
  uint32_t r = v.i + 0x7fffu + ((v.i >> 16) & 1u);   // round-nearest-even
  return (uint16_t)(r >> 16);
}
__device__ __forceinline__ float sigm(float x){ return 1.0f / (1.0f + __expf(-x)); }
__device__ __forceinline__ float tanh_(float x){
  float t = fminf(fmaxf(2.0f * x, -30.0f), 30.0f);
  float e = __expf(t);
  return (e - 1.0f) / (e + 1.0f);
}

// Split 8 fp32 (two f32x4) into bf16 hi + bf16 lo (residual) fragments.
__device__ __forceinline__ void split8v(const f32x4& a, const f32x4& b,
                                        bf16x8& hi8, bf16x8& lo8){
  float v[8] = {a[0], a[1], a[2], a[3], b[0], b[1], b[2], b[3]};
  #pragma unroll
  for (int j = 0; j < 8; ++j){
    uint16_t h = f2bf(v[j]);
    hi8[j] = (short)h;
    lo8[j] = (short)f2bf(v[j] - bf2f(h));
  }
}

// Coherent 16B load: sc0 sc1 -> bypass stale L1/L2, served at the LLC
// coherence point. volatile asm => issue order is program order, and the
// instruction is counted exactly once in vmcnt (counted waits rely on this).
__device__ __forceinline__ void cload16(const uint16_t* p, bf16x8& d){
  asm volatile("global_load_dwordx4 %0, %1, off sc0 sc1" : "=v"(d) : "v"(p));
}
// Normal cached 16B load (x input: read-only, coherent since kernel launch).
__device__ __forceinline__ void nload16(const float* p, f32x4& d){
  asm volatile("global_load_dwordx4 %0, %1, off" : "=v"(d) : "v"(p));
}
__device__ __forceinline__ void cstore16b(uint16_t* p, uint32_t v){
  asm volatile("global_store_short %0, %1, off sc0 sc1" :: "v"(p), "v"(v) : "memory");
}

#define WAITV(n) do { \
    asm volatile("s_waitcnt vmcnt(" #n ")" ::: "memory"); \
    __builtin_amdgcn_sched_barrier(0); \
  } while (0)

// Persistent LSTM. 128 blocks x 8 waves; block f owns h-cols [8f,8f+8).
// Gate tiles (N=16): tile0 = [H1|H2] (forget|input), tile1 = [H3|H4] (cand|out).
// K split across 8 waves (h:128 each, x:64 each); weights in VGPR/AGPR as bf16
// hi+lo pairs; A*W via 3 MFMAs (Ahi*Whi + Alo*Whi + Ahi*Wlo).
//
// Round-3: fuse the x-phase (loads + split8 + MFMA, ~2.5us serial VALU work)
// into the h-load pipeline's wait bubbles. One hand-unrolled issue order per
// step with exact counted vmcnt waits (in-order retirement):
//   issue h0,h1,x01 | W16 mfmaH0 | issue h2 | W16 mfmaH1 | issue h3 |
//   W16 xwork01+stash01 | W8 mfmaH2 | issue x23 | W8 mfmaH3 | W0 xwork23+stash23
// Top-of-step vmcnt(0) drain makes counts wave-uniform (wave0 carries a flag
// store; without the drain its counted waits would be off by one => garbage).
__global__ void __launch_bounds__(NTHR, 2) lstm_persist(
    const float* __restrict__ x,
    const float* __restrict__ X1, const float* __restrict__ H1, const float* __restrict__ b1,
    const float* __restrict__ X2, const float* __restrict__ H2, const float* __restrict__ b2,
    const float* __restrict__ X3, const float* __restrict__ H3, const float* __restrict__ b3,
    const float* __restrict__ X4, const float* __restrict__ H4, const float* __restrict__ b4,
    float* __restrict__ out, uint16_t* hbhi, uint16_t* hblo, int* done)
{
  __shared__ float part[8][64][36];   // stride 36: 2-way bank alias only
  const int tid  = threadIdx.x;
  const int w    = tid >> 6;          // wave 0..7
  const int L    = tid & 63;
  const int c    = L & 15;            // MFMA n / A-row-in-tile
  const int quad = L >> 4;
  const int cc   = c & 7;
  const int f    = blockIdx.x;
  const int colh = f * 8 + cc;        // owned h-column
  const bool hiHalf = (c >= 8);

  const float* W0 = hiHalf ? H2 : H1;
  const float* W1 = hiHalf ? H4 : H3;
  const float* V0 = hiHalf ? X2 : X1;
  const float* V1 = hiHalf ? X4 : X3;
  const float bias0 = (hiHalf ? b2 : b1)[colh];
  const float bias1 = (hiHalf ? b4 : b3)[colh];

  // --- one-time: weight fragments (B layout: n = lane&15, k = quad*8 + j) ---
  bf16x8 BhH0[4], BhL0[4], BhH1[4], BhL1[4];
  #pragma unroll
  for (int kk = 0; kk < 4; ++kk){
    const int kb = w*128 + kk*32 + quad*8;
    bf16x8 h0, l0, h1, l1;
    #pragma unroll
    for (int j = 0; j < 8; ++j){
      float w0 = W0[(size_t)(kb + j)*HD + colh];
      uint16_t a = f2bf(w0); h0[j] = (short)a; l0[j] = (short)f2bf(w0 - bf2f(a));
      float w1 = W1[(size_t)(kb + j)*HD + colh];
      uint16_t b_ = f2bf(w1); h1[j] = (short)b_; l1[j] = (short)f2bf(w1 - bf2f(b_));
    }
    BhH0[kk] = h0; BhL0[kk] = l0; BhH1[kk] = h1; BhL1[kk] = l1;
  }
  bf16x8 BxH0[2], BxL0[2], BxH1[2], BxL1[2];
  #pragma unroll
  for (int kk = 0; kk < 2; ++kk){
    const int kb = w*64 + kk*32 + quad*8;
    bf16x8 h0, l0, h1, l1;
    #pragma unroll
    for (int j = 0; j < 8; ++j){
      float w0 = V0[(size_t)(kb + j)*HD + colh];
      uint16_t a = f2bf(w0); h0[j] = (short)a; l0[j] = (short)f2bf(w0 - bf2f(a));
      float w1 = V1[(size_t)(kb + j)*HD + colh];
      uint16_t b_ = f2bf(w1); h1[j] = (short)b_; l1[j] = (short)f2bf(w1 - bf2f(b_));
    }
    BxH0[kk] = h0; BxL0[kk] = l0; BxH1[kk] = h1; BxL1[kk] = l1;
  }

  float cst[2] = {0.f, 0.f};

  #pragma unroll 1
  for (int t = 0; t < S_LEN; ++t){
    const int p = t & 1;
    f32x4 acc0[4], acc1[4];
    #pragma unroll
    for (int m = 0; m < 4; ++m){
      acc0[m] = (f32x4){0.f,0.f,0.f,0.f};
      acc1[m] = (f32x4){0.f,0.f,0.f,0.f};
    }

    // ---- wait: all blocks must have published h_t (done[b] >= t) ----
    if (t > 0){
      if (tid < NBLK){
        while (__hip_atomic_load(&done[tid*32], __ATOMIC_RELAXED, __HIP_MEMORY_SCOPE_AGENT) < t)
          __builtin_amdgcn_s_sleep(2);
      }
      __syncthreads();
    }

    const uint16_t* hbH = hbhi + (size_t)p * (64*HD);
    const uint16_t* hbL = hblo + (size_t)p * (64*HD);

    bf16x8 AH[2][4], AL[2][4];          // h A-fragments, double-buffered
    f32x4  xr[2][2][2];                 // x raw f32, [buf][kk][half]

    #define ISSUE_H(buf, m) do { \
      _Pragma("unroll") \
      for (int kk = 0; kk < 4; ++kk){ \
        const size_t off = (size_t)(16*(m) + c)*HD + w*128 + kk*32 + quad*8; \
        cload16(hbH + off, AH[buf][kk]); \
        cload16(hbL + off, AL[buf][kk]); \
      } } while(0)

    #define ISSUE_X(buf, m) do { \
      _Pragma("unroll") \
      for (int kk = 0; kk < 2; ++kk){ \
        const float* xp = x + ((size_t)(16*(m) + c)*S_LEN + t)*IDIM + w*64 + kk*32 + quad*8; \
        nload16(xp,     xr[buf][kk][0]); \
        nload16(xp + 4, xr[buf][kk][1]); \
      } } while(0)

    #define MFMA_H(buf, m) do { \
      _Pragma("unroll") \
      for (int kk = 0; kk < 4; ++kk){ \
        acc0[m] = MFMA16(AH[buf][kk], BhH0[kk], acc0[m], 0, 0, 0); \
        acc0[m] = MFMA16(AL[buf][kk], BhH0[kk], acc0[m], 0, 0, 0); \
        acc0[m] = MFMA16(AH[buf][kk], BhL0[kk], acc0[m], 0, 0, 0); \
        acc1[m] = MFMA16(AH[buf][kk], BhH1[kk], acc1[m], 0, 0, 0); \
        acc1[m] = MFMA16(AL[buf][kk], BhH1[kk], acc1[m], 0, 0, 0); \
        acc1[m] = MFMA16(AH[buf][kk], BhL1[kk], acc1[m], 0, 0, 0); \
      } } while(0)

    #define XWORK(buf, m) do { \
      _Pragma("unroll") \
      for (int kk = 0; kk < 2; ++kk){ \
        bf16x8 Ah, Al; split8v(xr[buf][kk][0], xr[buf][kk][1], Ah, Al); \
        acc0[m] = MFMA16(Ah, BxH0[kk], acc0[m], 0, 0, 0); \
        acc0[m] = MFMA16(Al, BxH0[kk], acc0[m], 0, 0, 0); \
        acc0[m] = MFMA16(Ah, BxL0[kk], acc0[m], 0, 0, 0); \
        acc1[m] = MFMA16(Ah, BxH1[kk], acc1[m], 0, 0, 0); \
        acc1[m] = MFMA16(Al, BxH1[kk], acc1[m], 0, 0, 0); \
        acc1[m] = MFMA16(Ah, BxL1[kk], acc1[m], 0, 0, 0); \
      } } while(0)

    #define STASH(m) do { \
      _Pragma("unroll") \
      for (int r = 0; r < 4; ++r){ \
        part[w][16*(m) + quad*4 + r][c]      = acc0[m][r]; \
        part[w][16*(m) + quad*4 + r][16 + c] = acc1[m][r]; \
      } } while(0)

    // drain leftovers (prev-step out stores; wave0's flag store) so vmcnt
    // counts below are exact and wave-uniform
    WAITV(0);
    // issue order (positions): h0:1-8  h1:9-16  x01:17-24
    ISSUE_H(0, 0);
    ISSUE_H(1, 1);
    ISSUE_X(0, 0);
    ISSUE_X(1, 1);
    WAITV(16);            // h0 ready
    MFMA_H(0, 0);
    ISSUE_H(0, 2);        // 25-32
    WAITV(16);            // h1 ready (x01,h2 outstanding)
    MFMA_H(1, 1);
    ISSUE_H(1, 3);        // 33-40
    WAITV(16);            // x01 ready (h2,h3 outstanding)
    XWORK(0, 0);
    XWORK(1, 1);
    STASH(0); STASH(1);   // rows 0,1 final; LDS writes fill the h2 wait
    WAITV(8);             // h2 ready (h3 outstanding)
    MFMA_H(0, 2);
    ISSUE_X(0, 2);        // 41-44
    ISSUE_X(1, 3);        // 45-48
    WAITV(8);             // h3 ready (x23 outstanding)
    MFMA_H(1, 3);
    WAITV(0);             // x23 ready
    XWORK(0, 2);
    XWORK(1, 3);
    STASH(2); STASH(3);

    #undef ISSUE_H
    #undef ISSUE_X
    #undef MFMA_H
    #undef XWORK
    #undef STASH

    __syncthreads();

    // ---- cross-wave K-reduction; wave w handles batch rows [8w,8w+8) ----
    float g0[2], g1[2];
    #pragma unroll
    for (int r2 = 0; r2 < 2; ++r2){
      const int row = 8*w + quad*2 + r2;
      float a = bias0, b = bias1;
      #pragma unroll
      for (int ww = 0; ww < 8; ++ww){
        a += part[ww][row][c];
        b += part[ww][row][16 + c];
      }
      g0[r2] = a; g1[r2] = b;
    }

    // ---- gates (lane c<8 holds forget/cand; partner c+8 holds input/output) ----
    uint16_t* hwH = hbhi + (size_t)(p^1) * (64*HD);
    uint16_t* hwL = hblo + (size_t)(p^1) * (64*HD);
    float hv[2];
    #pragma unroll
    for (int r2 = 0; r2 < 2; ++r2){
      float gf = g0[r2];
      float gi = __shfl_xor(g0[r2], 8, 64);
      float gc = g1[r2];
      float go = __shfl_xor(g1[r2], 8, 64);
      float cn = cst[r2] * sigm(gf) + sigm(gi) * tanh_(gc);
      cst[r2] = cn;
      hv[r2] = tanh_(cn) * sigm(go);
    }
    if (!hiHalf){
      #pragma unroll
      for (int r2 = 0; r2 < 2; ++r2){
        const int batch = 8*w + quad*2 + r2;
        uint16_t hh = f2bf(hv[r2]);
        uint16_t hl = f2bf(hv[r2] - bf2f(hh));
        cstore16b(hwH + (size_t)batch*HD + colh, (uint32_t)hh);
        cstore16b(hwL + (size_t)batch*HD + colh, (uint32_t)hl);
      }
    }

    // ---- publish: drain write-through h stores, converge, flag store ----
    asm volatile("s_waitcnt vmcnt(0)" ::: "memory");
    __syncthreads();
    if (tid == 0)
      __hip_atomic_store(&done[f*32], t + 1, __ATOMIC_RELAXED, __HIP_MEMORY_SCOPE_AGENT);

    // ---- out stores OFF the critical publish path ----
    if (!hiHalf){
      #pragma unroll
      for (int r2 = 0; r2 < 2; ++r2){
        const int batch = 8*w + quad*2 + r2;
        __builtin_nontemporal_store(hv[r2], &out[(size_t)(batch*S_LEN + t)*HD + colh]);
      }
    }
  }
}

extern "C" void kernel_launch(void* const* d_in, const int* in_sizes, int n_in,
                              void* d_out, int out_size, void* d_ws, size_t ws_size,
                              hipStream_t stream) {
  const float* x  = (const float*)d_in[0];
  const float* X1 = (const float*)d_in[1];
  const float* H1 = (const float*)d_in[2];
  const float* b1 = (const float*)d_in[3];
  const float* X2 = (const float*)d_in[4];
  const float* H2 = (const float*)d_in[5];
  const float* b2 = (const float*)d_in[6];
  const float* X3 = (const float*)d_in[7];
  const float* H3 = (const float*)d_in[8];
  const float* b3 = (const float*)d_in[9];
  const float* X4 = (const float*)d_in[10];
  const float* H4 = (const float*)d_in[11];
  const float* b4 = (const float*)d_in[12];
  float* out = (float*)d_out;

  // ws: hbhi [2][64][1024] bf16 (262144 B) | hblo same | done[128] @128B stride
  uint16_t* hbhi = (uint16_t*)d_ws;
  uint16_t* hblo = (uint16_t*)((char*)d_ws + 262144);
  int* done      = (int*)((char*)d_ws + 524288);
  hipMemsetAsync(d_ws, 0, 524288 + 16384, stream);   // h0 = 0 (hi/lo), flags = 0

  hipLaunchKernelGGL(lstm_persist, dim3(NBLK), dim3(NTHR), 0, stream,
                     x, X1, H1, b1, X2, H2, b2, X3, H3, b3, X4, H4, b4,
                     out, hbhi, hblo, done);
}